// Round 10
// baseline (863.758 us; speedup 1.0000x reference)
//
#include <hip/hip_runtime.h>
#include <hip/hip_bf16.h>
#include <cstdint>
#include <cstddef>

#define Bsz 16384
#define HORsz 5

using bf16_t = __hip_bfloat16;
typedef __bf16 bf16x8 __attribute__((ext_vector_type(8)));
typedef float f32x4 __attribute__((ext_vector_type(4)));

__device__ __forceinline__ void gld_lds16(const void* g, void* l) {
  __builtin_amdgcn_global_load_lds((__attribute__((address_space(1))) void*)g,
                                   (__attribute__((address_space(3))) void*)l,
                                   16, 0, 0);
}

__device__ __forceinline__ float sigm(float x) { return 1.f / (1.f + __expf(-x)); }
__device__ __forceinline__ float tanh_fast(float x) {
  x = fminf(fmaxf(x, -20.f), 20.f);
  float e = __expf(2.f * x);
  return (e - 1.f) / (e + 1.f);
}

// VALU-pipe 16-lane-group sum via DPP (no DS ops; frees the LDS pipe).
template <int CTRL>
__device__ __forceinline__ float dpp_add(float v) {
  int x = __builtin_amdgcn_update_dpp(0, __float_as_int(v), CTRL, 0xF, 0xF, true);
  return v + __int_as_float(x);
}
__device__ __forceinline__ float red16(float v) {
  v = dpp_add<0xB1>(v);
  v = dpp_add<0x4E>(v);
  v = dpp_add<0x124>(v);
  v = dpp_add<0x128>(v);
  return v;
}

// XCD-aware swizzle: blocks b, b+8, b+16 ... (same XCD under b%8 round-robin)
__device__ __forceinline__ void swz(int b, int nbn, int& n, int& m) {
  const int x = b & 7;
  const int k = b >> 3;
  n = k % nbn;
  m = x + 8 * (k / nbn);
}

// Fragment layout (FL) bf16 [R,C]: 1KB chunk = 16 rows x 32 cols; lane l <-> bytes [16l,16l+16).
__device__ __forceinline__ size_t fl_off(int row, int col, int ca, int cofs) {
  return (size_t)((row >> 4) * ca + cofs + (col >> 5)) * 1024
       + (size_t)((((col >> 3) & 3) * 16 + (row & 15)) * 16 + (col & 7) * 2);
}

// fp32 row-major [R,C] -> bf16 FL.
__global__ void __launch_bounds__(256) pack_fl(const float* __restrict__ src,
                                               char* __restrict__ dst,
                                               int C, int cs, int npieces) {
  const int p = blockIdx.x * 256 + threadIdx.x;
  if (p >= npieces) return;
  const int chunk = p >> 6, wi = p & 63;
  const int colgrp = wi >> 4, r15 = wi & 15;
  const int rowgrp = chunk >> cs, kg = chunk & ((1 << cs) - 1);
  const int row = rowgrp * 16 + r15;
  const int col = kg * 32 + colgrp * 8;
  const float* s = src + (size_t)row * C + col;
  bf16x8 v;
  #pragma unroll
  for (int j = 0; j < 8; ++j) v[j] = (__bf16)s[j];
  *(bf16x8*)(dst + (size_t)p * 16) = v;
}

// Pack x rows into padded FL K-chunk: cols 0-3 = x, col 4 = 1.0, cols 5-31 = 0.
// One thread per (slice, row); slice stride 1 MB (1024 chunks).
__global__ void __launch_bounds__(256) pack_x(const float* __restrict__ src, int ld,
                                              char* __restrict__ dst, int ntot) {
  const int p = blockIdx.x * 256 + threadIdx.x;
  if (p >= ntot) return;
  const int slice = p >> 14, row = p & 16383;
  const float* s = src + (size_t)row * ld + slice * 4;
  bf16x8 v;
  v[0] = (__bf16)s[0]; v[1] = (__bf16)s[1]; v[2] = (__bf16)s[2]; v[3] = (__bf16)s[3];
  v[4] = (__bf16)1.0f; v[5] = (__bf16)0.f; v[6] = (__bf16)0.f; v[7] = (__bf16)0.f;
  char* base = dst + (size_t)slice * 1048576 + (size_t)(row >> 4) * 1024 + (row & 15) * 16;
  const bf16x8 z = {};
  *(bf16x8*)(base) = v;
  *(bf16x8*)(base + 256) = z;
  *(bf16x8*)(base + 512) = z;
  *(bf16x8*)(base + 768) = z;
}

// Pack w_ih [1536,4] + biases into the matching W-side K-chunk:
// cols 0-3 = w_ih, col 4 = b_ih (+ b_hh for r,z rows; n-gate's b_hh stays in epilogue).
__global__ void __launch_bounds__(256) pack_wih(const float* __restrict__ w_ih,
                                                const float* __restrict__ b_ih,
                                                const float* __restrict__ b_hh,
                                                char* __restrict__ dst) {
  const int row = blockIdx.x * 256 + threadIdx.x;
  if (row >= 1536) return;
  const float* s = w_ih + (size_t)row * 4;
  const float c4 = b_ih[row] + (row < 1024 ? b_hh[row] : 0.f);
  bf16x8 v;
  v[0] = (__bf16)s[0]; v[1] = (__bf16)s[1]; v[2] = (__bf16)s[2]; v[3] = (__bf16)s[3];
  v[4] = (__bf16)c4;   v[5] = (__bf16)0.f; v[6] = (__bf16)0.f; v[7] = (__bf16)0.f;
  char* base = dst + (size_t)(row >> 4) * 1024 + (row & 15) * 16;
  const bf16x8 z = {};
  *(bf16x8*)(base) = v;
  *(bf16x8*)(base + 256) = z;
  *(bf16x8*)(base + 512) = z;
  *(bf16x8*)(base + 768) = z;
}

// Fused GRU cell. Block: 64 rows x 64 chans x 3 gates. K-step 32, dbuf 2x16KB.
// NEW: x@w_ih^T + b_ih (+b_hh for r,z) folded into MFMA via a 17th K-chunk
// ([x|1] FL x [w_ih|b] FL). n-gate's input part goes to separate acc_ni
// (n = tanh(i_n + r*h_n) needs the split). Epilogue: no x/w_ih loads, ~60%
// less VALU — gru was VALUBusy 45% vs MfmaUtil 22% (round-9 profile).
__global__ void __launch_bounds__(256, 3) gru_fused5(
    const char* __restrict__ Afl, int ca,   // A = hprev FL, K chunks 0..15
    const char* __restrict__ Wfl,           // whh FL [1536,512], nkg=16
    const char* __restrict__ xF,            // [x|1] FL chunks, 1/rowgrp (1KB stride)
    const char* __restrict__ wihF,          // [w_ih|b] FL chunks, 1/W-rowgrp
    const float* __restrict__ b_hh,
    char* __restrict__ Ofl, int co, int kofs)
{
  __shared__ char smem[32768];
  const int t = threadIdx.x, w = t >> 6, lane = t & 63;
  int bn, bm;
  swz(blockIdx.x, 8, bn, bm);
  const int m0 = bm * 64;
  const int n0 = bn * 64;

  // 16 chunk-slots per K-step: 0..3 = A rowgrps, 4..15 = W (gate g, colgrp cr)
  const char* gsrc[4];
  const char* gsrc16[4];
  int loff[4];
  #pragma unroll
  for (int s = 0; s < 4; ++s) {
    const int idx = w * 4 + s;
    if (idx < 4) {
      gsrc[s]   = Afl + (size_t)((m0 >> 4) + idx) * ca * 1024 + lane * 16;
      gsrc16[s] = xF  + (size_t)((m0 >> 4) + idx) * 1024 + lane * 16;
    } else {
      const int c = idx - 4, g = c >> 2, cr = c & 3;
      gsrc[s]   = Wfl  + (size_t)(g * 32 + (n0 >> 4) + cr) * 16 * 1024 + lane * 16;
      gsrc16[s] = wihF + (size_t)(g * 32 + (n0 >> 4) + cr) * 1024 + lane * 16;
    }
    loff[s] = idx * 1024;
  }

  f32x4 acc[3][4], acc_ni[4];
  const f32x4 zero = {0.f, 0.f, 0.f, 0.f};
  #pragma unroll
  for (int g = 0; g < 3; ++g)
    #pragma unroll
    for (int i = 0; i < 4; ++i) acc[g][i] = zero;
  #pragma unroll
  for (int i = 0; i < 4; ++i) acc_ni[i] = zero;

  #pragma unroll
  for (int s = 0; s < 4; ++s)
    gld_lds16(gsrc[s], smem + loff[s]);

  #pragma unroll
  for (int kg = 0; kg < 16; ++kg) {
    __syncthreads();   // stage(kg) drained
    const char* cur = smem + (kg & 1) * 16384;
    char* nxt = smem + ((kg + 1) & 1) * 16384;
    if (kg + 1 < 16) {
      #pragma unroll
      for (int s = 0; s < 4; ++s)
        gld_lds16(gsrc[s] + (size_t)(kg + 1) * 1024, nxt + loff[s]);
    } else {
      // stage the extra [x|1]/[w_ih|b] chunk into buf0 (= ((16)&1)*16384)
      #pragma unroll
      for (int s = 0; s < 4; ++s)
        gld_lds16(gsrc16[s], nxt + loff[s]);
    }
    bf16x8 af[4];
    #pragma unroll
    for (int i = 0; i < 4; ++i)
      af[i] = *(const bf16x8*)(cur + i * 1024 + lane * 16);
    #pragma unroll
    for (int g = 0; g < 3; ++g) {
      const bf16x8 bv = *(const bf16x8*)(cur + (4 + g * 4 + w) * 1024 + lane * 16);
      #pragma unroll
      for (int i = 0; i < 4; ++i)
        acc[g][i] = __builtin_amdgcn_mfma_f32_16x16x32_bf16(af[i], bv, acc[g][i], 0, 0, 0);
    }
  }

  // extra K-step: x-part. r,z accumulate in place; n-part to acc_ni.
  __syncthreads();
  {
    const char* cur = smem;   // buf0
    bf16x8 af[4];
    #pragma unroll
    for (int i = 0; i < 4; ++i)
      af[i] = *(const bf16x8*)(cur + i * 1024 + lane * 16);
    #pragma unroll
    for (int g = 0; g < 2; ++g) {
      const bf16x8 bv = *(const bf16x8*)(cur + (4 + g * 4 + w) * 1024 + lane * 16);
      #pragma unroll
      for (int i = 0; i < 4; ++i)
        acc[g][i] = __builtin_amdgcn_mfma_f32_16x16x32_bf16(af[i], bv, acc[g][i], 0, 0, 0);
    }
    const bf16x8 bv2 = *(const bf16x8*)(cur + (4 + 8 + w) * 1024 + lane * 16);
    #pragma unroll
    for (int i = 0; i < 4; ++i)
      acc_ni[i] = __builtin_amdgcn_mfma_f32_16x16x32_bf16(af[i], bv2, acc_ni[i], 0, 0, 0);
  }
  __syncthreads();  // all waves done reading buf0 before rep overwrites it

  const int lr = lane & 15, q4 = (lane >> 4) * 4;
  char* rep = smem + w * 2048;  // 4 half-chunks x 512B, wave-private (in buf0)
  const int c = n0 + w * 16 + lr;
  const float bhn = b_hh[c + 1024];
  const int wbase = ((lr >> 3) * 16 + q4) * 16 + (lr & 7) * 2;
  #pragma unroll
  for (int i = 0; i < 4; ++i) {
    #pragma unroll
    for (int r4 = 0; r4 < 4; ++r4) {
      const int row = m0 + i * 16 + q4 + r4;
      const float rr = sigm(acc[0][i][r4]);
      const float zz = sigm(acc[1][i][r4]);
      const float nn = tanh_fast(acc_ni[i][r4] + rr * (acc[2][i][r4] + bhn));
      const float hp = (float)*(const __bf16*)(Afl + fl_off(row, c, ca, 0));
      *(__bf16*)(rep + i * 512 + wbase + r4 * 16) = (__bf16)((1.f - zz) * nn + zz * hp);
    }
  }
  const int rg0 = m0 >> 4;
  const int cg = kofs + (n0 >> 5) + (w >> 1);
  const int half = (w & 1) * 512;
  #pragma unroll
  for (int i = 0; i < 4; ++i) {
    const uint2 v = *(const uint2*)(rep + i * 512 + lane * 8);
    *(uint2*)(Ofl + ((size_t)(rg0 + i) * co + cg) * 1024 + half + lane * 8) = v;
  }
}

// Generic FL GEMM (round-0). Block tile 128 x (NJ*32); wave tile 64 x (NJ*16).
// MODE 2 (fc): O1 = bf16(v) FL ; O2 = bf16(relu(v)) FL — coalesced via LDS repack
template <int NKG, int NJ, int MODE>
__global__ void __launch_bounds__(256, 4) gemm_fl5(
    const char* __restrict__ Afl,
    const char* __restrict__ Bfl, int nbn,
    const float* __restrict__ bias,
    char* __restrict__ O1, char* __restrict__ O2, int co,
    const float* __restrict__ w2, float* __restrict__ dxy)
{
  constexpr int NCH = 8 + 2 * NJ;          // chunks staged per K-step
  constexpr int NS = NCH / 4;              // chunks per wave
  constexpr int BUFB = NCH * 1024;
  __shared__ char smem[2 * BUFB];
  const int t = threadIdx.x, w = t >> 6, lane = t & 63;
  int bn, bm;
  swz(blockIdx.x, nbn, bn, bm);
  const int m0 = bm * 128, n0 = bn * (NJ * 32);
  const int wm = (w >> 1) * 64, wn = (w & 1) * (NJ * 16);

  const char* gsrc[NS];
  int loff[NS];
  #pragma unroll
  for (int s = 0; s < NS; ++s) {
    const int idx = w * NS + s;
    if (idx < 8) gsrc[s] = Afl + (size_t)((m0 >> 4) + idx) * NKG * 1024 + lane * 16;
    else         gsrc[s] = Bfl + (size_t)((n0 >> 4) + idx - 8) * NKG * 1024 + lane * 16;
    loff[s] = idx * 1024;
  }

  f32x4 acc[4][NJ];
  const f32x4 zero = {0.f, 0.f, 0.f, 0.f};
  #pragma unroll
  for (int i = 0; i < 4; ++i)
    #pragma unroll
    for (int j = 0; j < NJ; ++j) acc[i][j] = zero;

  #pragma unroll
  for (int s = 0; s < NS; ++s)
    gld_lds16(gsrc[s], smem + loff[s]);

  #pragma unroll
  for (int kg = 0; kg < NKG; ++kg) {
    __syncthreads();
    const char* cur = smem + (kg & 1) * BUFB;
    if (kg + 1 < NKG) {
      char* nxt = smem + ((kg + 1) & 1) * BUFB;
      #pragma unroll
      for (int s = 0; s < NS; ++s)
        gld_lds16(gsrc[s] + (size_t)(kg + 1) * 1024, nxt + loff[s]);
    }
    bf16x8 af[4], bv[NJ];
    #pragma unroll
    for (int i = 0; i < 4; ++i)
      af[i] = *(const bf16x8*)(cur + ((wm >> 4) + i) * 1024 + lane * 16);
    #pragma unroll
    for (int j = 0; j < NJ; ++j)
      bv[j] = *(const bf16x8*)(cur + (8 + (wn >> 4) + j) * 1024 + lane * 16);
    #pragma unroll
    for (int i = 0; i < 4; ++i)
      #pragma unroll
      for (int j = 0; j < NJ; ++j)
        acc[i][j] = __builtin_amdgcn_mfma_f32_16x16x32_bf16(af[i], bv[j], acc[i][j], 0, 0, 0);
  }

  const int lr = lane & 15, q4 = (lane >> 4) * 4;
  if (MODE == 2) {
    char* rep = smem + w * (NJ / 2) * 1024;
    const int rgb = (m0 >> 4) + (wm >> 4);
    const int cgb = (n0 >> 5) + (wn >> 5);
    for (int i = 0; i < 4; ++i) {
      #pragma unroll
      for (int j = 0; j < NJ; ++j) {
        const int col = n0 + wn + j * 16 + lr;
        const float bvv = bias[col];
        const int wbase = (((j & 1) * 2 + (lr >> 3)) * 16 + q4) * 16 + (lr & 7) * 2;
        #pragma unroll
        for (int r = 0; r < 4; ++r) {
          const float v = acc[i][j][r] + bvv;
          *(__bf16*)(rep + (j >> 1) * 1024 + wbase + r * 16) = (__bf16)v;
        }
      }
      #pragma unroll
      for (int jc = 0; jc < NJ / 2; ++jc) {
        const bf16x8 v = *(const bf16x8*)(rep + jc * 1024 + lane * 16);
        const size_t cb = ((size_t)(rgb + i) * co + cgb + jc) * 1024 + lane * 16;
        *(bf16x8*)(O1 + cb) = v;
        bf16x8 vr;
        #pragma unroll
        for (int e = 0; e < 8; ++e) vr[e] = (__bf16)fmaxf((float)v[e], 0.f);
        *(bf16x8*)(O2 + cb) = vr;
      }
    }
  }
}

// MLP GEMM (+relu+w2 fusion), 8-wave 256x256 tile, BK=32, K=512 (NKG=16).
// 2-buffer (64KB LDS); DPP/VALU-pipe epilogue (round-9 confirmed: −20% vs shuffle).
__global__ void __launch_bounds__(512, 2) mlp2b(
    const char* __restrict__ Afl,   // hxrF FL, nkg=16
    const char* __restrict__ Bfl,   // w1F  FL, nkg=16
    const float* __restrict__ bias, // b1
    const float* __restrict__ w2,   // [4,2048]
    float* __restrict__ dxy)
{
  __shared__ char smem[2 * 32768];
  const int t = threadIdx.x, w = t >> 6, lane = t & 63;
  const int wr = w >> 2, wc = w & 3;
  int bn, bm;
  swz(blockIdx.x, 8, bn, bm);
  const int m0 = bm * 256, n0 = bn * 256;

  const char* gsrc[4];
  int loff[4];
  #pragma unroll
  for (int s = 0; s < 4; ++s) {
    const int idx = w * 4 + s;
    if (idx < 16) {
      gsrc[s] = Afl + (size_t)((m0 >> 4) + idx) * 16 * 1024 + lane * 16;
      loff[s] = idx * 1024;
    } else {
      gsrc[s] = Bfl + (size_t)((n0 >> 4) + idx - 16) * 16 * 1024 + lane * 16;
      loff[s] = 16384 + (idx - 16) * 1024;
    }
  }

  f32x4 acc[8][4];
  const f32x4 zero = {0.f, 0.f, 0.f, 0.f};
  #pragma unroll
  for (int i = 0; i < 8; ++i)
    #pragma unroll
    for (int j = 0; j < 4; ++j) acc[i][j] = zero;

  #pragma unroll
  for (int s = 0; s < 4; ++s)
    gld_lds16(gsrc[s], smem + loff[s]);

  #pragma unroll
  for (int kg = 0; kg < 16; ++kg) {
    __syncthreads();
    const char* cur = smem + (kg & 1) * 32768;
    if (kg + 1 < 16) {
      char* nxt = smem + ((kg + 1) & 1) * 32768;
      #pragma unroll
      for (int s = 0; s < 4; ++s)
        gld_lds16(gsrc[s] + (size_t)(kg + 1) * 1024, nxt + loff[s]);
    }
    bf16x8 af[8], bv[4];
    #pragma unroll
    for (int j = 0; j < 4; ++j)
      bv[j] = *(const bf16x8*)(cur + 16384 + (wc * 4 + j) * 1024 + lane * 16);
    #pragma unroll
    for (int i = 0; i < 8; ++i)
      af[i] = *(const bf16x8*)(cur + (wr * 8 + i) * 1024 + lane * 16);
    __builtin_amdgcn_s_setprio(1);
    #pragma unroll
    for (int i = 0; i < 8; ++i)
      #pragma unroll
      for (int j = 0; j < 4; ++j)
        acc[i][j] = __builtin_amdgcn_mfma_f32_16x16x32_bf16(af[i], bv[j], acc[i][j], 0, 0, 0);
    __builtin_amdgcn_s_setprio(0);
  }

  const int lr = lane & 15, q4 = (lane >> 4) * 4;
  const int slice = bn * 4 + wc;
  float bvv[4], w2c[4][4];
  #pragma unroll
  for (int j = 0; j < 4; ++j) {
    const int col = n0 + wc * 64 + j * 16 + lr;
    bvv[j] = bias[col];
    w2c[j][0] = w2[col];        w2c[j][1] = w2[2048 + col];
    w2c[j][2] = w2[4096 + col]; w2c[j][3] = w2[6144 + col];
  }
  #pragma unroll
  for (int i = 0; i < 8; ++i) {
    float v[4][4];
    #pragma unroll
    for (int r = 0; r < 4; ++r)
      #pragma unroll
      for (int o = 0; o < 4; ++o) v[r][o] = 0.f;
    #pragma unroll
    for (int j = 0; j < 4; ++j) {
      #pragma unroll
      for (int r = 0; r < 4; ++r) {
        const float pv = fmaxf(acc[i][j][r] + bvv[j], 0.f);
        v[r][0] += pv * w2c[j][0]; v[r][1] += pv * w2c[j][1];
        v[r][2] += pv * w2c[j][2]; v[r][3] += pv * w2c[j][3];
      }
    }
    #pragma unroll
    for (int r = 0; r < 4; ++r)
      #pragma unroll
      for (int o = 0; o < 4; ++o) v[r][o] = red16(v[r][o]);
    if (lr == 0) {
      #pragma unroll
      for (int r = 0; r < 4; ++r) {
        const int row = m0 + wr * 128 + i * 16 + q4 + r;
        float4 vv = make_float4(v[r][0], v[r][1], v[r][2], v[r][3]);
        *(float4*)(dxy + ((size_t)slice * Bsz + row) * 4) = vv;
      }
    }
  }
}

// xy += sum(dxy slices) + b2; out[:,istep,:] = xy; also refresh xyF ([xy|1] FL chunk).
__global__ void __launch_bounds__(256) finalize(
    const float* __restrict__ dxy, const float* __restrict__ b2,
    float* __restrict__ xy, float* __restrict__ out, int istep,
    char* __restrict__ xyF)
{
  const int b = blockIdx.x * 256 + threadIdx.x;
  float4 s = *(const float4*)b2;
  #pragma unroll 8
  for (int sl = 0; sl < 32; ++sl) {
    const float4 d = *(const float4*)(dxy + ((size_t)sl * Bsz + b) * 4);
    s.x += d.x; s.y += d.y; s.z += d.z; s.w += d.w;
  }
  float4 xv = *(const float4*)(xy + (size_t)b * 4);
  xv.x += s.x; xv.y += s.y; xv.z += s.z; xv.w += s.w;
  *(float4*)(xy + (size_t)b * 4) = xv;
  *(float4*)(out + (size_t)b * 20 + istep * 4) = xv;
  bf16x8 v;
  v[0] = (__bf16)xv.x; v[1] = (__bf16)xv.y; v[2] = (__bf16)xv.z; v[3] = (__bf16)xv.w;
  v[4] = (__bf16)1.0f; v[5] = (__bf16)0.f; v[6] = (__bf16)0.f; v[7] = (__bf16)0.f;
  *(bf16x8*)(xyF + (size_t)(b >> 4) * 1024 + (b & 15) * 16) = v;
}

extern "C" void kernel_launch(void* const* d_in, const int* in_sizes, int n_in,
                              void* d_out, int out_size, void* d_ws, size_t ws_size,
                              hipStream_t stream)
{
  const float* pv   = (const float*)d_in[0];
  const float* ptf  = (const float*)d_in[1];
  const float* w_ih = (const float*)d_in[2];
  const float* w_hh = (const float*)d_in[3];
  const float* b_ih = (const float*)d_in[4];
  const float* b_hh = (const float*)d_in[5];
  const float* w_fc = (const float*)d_in[6];
  const float* b_fc = (const float*)d_in[7];
  const float* w1   = (const float*)d_in[8];
  const float* b1   = (const float*)d_in[9];
  const float* w2   = (const float*)d_in[10];
  const float* b2   = (const float*)d_in[11];
  float* out = (float*)d_out;

  char* p = (char*)d_ws;
  auto carve = [&](size_t bytes) {
    char* r = p;
    p += (bytes + 255) & ~(size_t)255;
    return r;
  };
  char*  hxF   = carve((size_t)Bsz * 512 * 2);     // FL ca=16
  char*  hxrF  = carve((size_t)Bsz * 512 * 2);     // FL ca=16
  char*  hcatF = carve((size_t)Bsz * 1024 * 2);    // FL ca=32: h1 kg 0..15, h2 kg 16..31
  float* dxy   = (float*)carve((size_t)32 * Bsz * 4 * 4);
  float* xy    = (float*)carve((size_t)Bsz * 4 * 4);
  char*  whhF  = carve((size_t)1536 * 512 * 2);    // FL nkg=16
  char*  wfcF  = carve((size_t)512 * 1024 * 2);    // FL nkg=32
  char*  w1F   = carve((size_t)2048 * 512 * 2);    // FL nkg=16
  char*  xyF   = carve((size_t)1024 * 1024);       // [xy|1] FL chunks
  char*  pvF   = carve((size_t)5 * 1024 * 1024);   // [pv_i|1] FL chunks, 1MB/slice
  char*  wihF  = carve((size_t)96 * 1024);         // [w_ih|b] FL chunks

  pack_fl<<<(1536 * 512 / 8 + 255) / 256, 256, 0, stream>>>(w_hh, whhF, 512, 4, 1536 * 512 / 8);
  pack_fl<<<(512 * 1024 / 8 + 255) / 256, 256, 0, stream>>>(w_fc, wfcF, 1024, 5, 512 * 1024 / 8);
  pack_fl<<<(2048 * 512 / 8 + 255) / 256, 256, 0, stream>>>(w1, w1F, 512, 4, 2048 * 512 / 8);
  pack_fl<<<(Bsz * 512 / 8 + 255) / 256, 256, 0, stream>>>(ptf, hxF, 512, 4, Bsz * 512 / 8);
  pack_wih<<<6, 256, 0, stream>>>(w_ih, b_ih, b_hh, wihF);
  pack_x<<<(Bsz * HORsz + 255) / 256, 256, 0, stream>>>(pv, HORsz * 4, pvF, Bsz * HORsz);
  hipMemsetAsync(xy, 0, (size_t)Bsz * 4 * 4, stream);
  pack_x<<<Bsz / 256, 256, 0, stream>>>(xy, 4, xyF, Bsz);   // xy=0 -> cols 0-3=0, col4=1

  for (int i = 0; i < HORsz; ++i) {
    // h1 = GRUCell(xy, hx) -> hcat kg 0..15
    gru_fused5<<<2048, 256, 0, stream>>>(
        hxF, 16, whhF, xyF, wihF, b_hh, hcatF, 32, 0);
    // h2 = GRUCell(pv[:,i], h1) -> hcat kg 16..31
    gru_fused5<<<2048, 256, 0, stream>>>(
        hcatF, 32, whhF, pvF + (size_t)i * 1048576, wihF, b_hh, hcatF, 32, 16);
    // hx = hcat @ w_fc^T + b_fc ; hxr = relu(hx)
    gemm_fl5<32, 2, 2><<<1024, 256, 0, stream>>>(
        hcatF, wfcF, 8, b_fc, hxF, hxrF, 16, nullptr, nullptr);
    // dxy partials = relu(relu-gemm) @ w2^T  (256^2 8-wave, DPP epilogue)
    mlp2b<<<512, 512, 0, stream>>>(hxrF, w1F, b1, w2, dxy);
    // xy += sum + b2; out; refresh xyF
    finalize<<<Bsz / 256, 256, 0, stream>>>(dxy, b2, xy, out, i, xyF);
  }
}

// Round 11
// 766.833 us; speedup vs baseline: 1.1264x; 1.1264x over previous
//
#include <hip/hip_runtime.h>
#include <hip/hip_bf16.h>
#include <cstdint>
#include <cstddef>

#define Bsz 16384
#define HORsz 5

using bf16_t = __hip_bfloat16;
typedef __bf16 bf16x8 __attribute__((ext_vector_type(8)));
typedef float f32x4 __attribute__((ext_vector_type(4)));

__device__ __forceinline__ void gld_lds16(const void* g, void* l) {
  __builtin_amdgcn_global_load_lds((__attribute__((address_space(1))) void*)g,
                                   (__attribute__((address_space(3))) void*)l,
                                   16, 0, 0);
}

// Counted vmem wait: literal-only operand, dispatch via if constexpr.
template <int N>
__device__ __forceinline__ void wait_vmcnt() {
  if constexpr (N == 0)      asm volatile("s_waitcnt vmcnt(0)" ::: "memory");
  else if constexpr (N == 4) asm volatile("s_waitcnt vmcnt(4)" ::: "memory");
  else static_assert(N == 0 || N == 4, "unsupported vmcnt");
}

__device__ __forceinline__ float sigm(float x) { return 1.f / (1.f + __expf(-x)); }
__device__ __forceinline__ float tanh_fast(float x) {
  x = fminf(fmaxf(x, -20.f), 20.f);
  float e = __expf(2.f * x);
  return (e - 1.f) / (e + 1.f);
}

// VALU-pipe 16-lane-group sum via DPP (no DS ops; frees the LDS pipe).
template <int CTRL>
__device__ __forceinline__ float dpp_add(float v) {
  int x = __builtin_amdgcn_update_dpp(0, __float_as_int(v), CTRL, 0xF, 0xF, true);
  return v + __int_as_float(x);
}
__device__ __forceinline__ float red16(float v) {
  v = dpp_add<0xB1>(v);
  v = dpp_add<0x4E>(v);
  v = dpp_add<0x124>(v);
  v = dpp_add<0x128>(v);
  return v;
}

// XCD-aware swizzle: blocks b, b+8, b+16 ... (same XCD under b%8 round-robin)
__device__ __forceinline__ void swz(int b, int nbn, int& n, int& m) {
  const int x = b & 7;
  const int k = b >> 3;
  n = k % nbn;
  m = x + 8 * (k / nbn);
}

// Fragment layout (FL) bf16 [R,C]: 1KB chunk = 16 rows x 32 cols; lane l <-> bytes [16l,16l+16).
__device__ __forceinline__ size_t fl_off(int row, int col, int ca, int cofs) {
  return (size_t)((row >> 4) * ca + cofs + (col >> 5)) * 1024
       + (size_t)((((col >> 3) & 3) * 16 + (row & 15)) * 16 + (col & 7) * 2);
}

// fp32 row-major [R,C] -> bf16 FL.
__global__ void __launch_bounds__(256) pack_fl(const float* __restrict__ src,
                                               char* __restrict__ dst,
                                               int C, int cs, int npieces) {
  const int p = blockIdx.x * 256 + threadIdx.x;
  if (p >= npieces) return;
  const int chunk = p >> 6, wi = p & 63;
  const int colgrp = wi >> 4, r15 = wi & 15;
  const int rowgrp = chunk >> cs, kg = chunk & ((1 << cs) - 1);
  const int row = rowgrp * 16 + r15;
  const int col = kg * 32 + colgrp * 8;
  const float* s = src + (size_t)row * C + col;
  bf16x8 v;
  #pragma unroll
  for (int j = 0; j < 8; ++j) v[j] = (__bf16)s[j];
  *(bf16x8*)(dst + (size_t)p * 16) = v;
}

// Pack x rows into padded FL K-chunk: cols 0-3 = x, col 4 = 1.0, cols 5-31 = 0.
__global__ void __launch_bounds__(256) pack_x(const float* __restrict__ src, int ld,
                                              char* __restrict__ dst, int ntot) {
  const int p = blockIdx.x * 256 + threadIdx.x;
  if (p >= ntot) return;
  const int slice = p >> 14, row = p & 16383;
  const float* s = src + (size_t)row * ld + slice * 4;
  bf16x8 v;
  v[0] = (__bf16)s[0]; v[1] = (__bf16)s[1]; v[2] = (__bf16)s[2]; v[3] = (__bf16)s[3];
  v[4] = (__bf16)1.0f; v[5] = (__bf16)0.f; v[6] = (__bf16)0.f; v[7] = (__bf16)0.f;
  char* base = dst + (size_t)slice * 1048576 + (size_t)(row >> 4) * 1024 + (row & 15) * 16;
  const bf16x8 z = {};
  *(bf16x8*)(base) = v;
  *(bf16x8*)(base + 256) = z;
  *(bf16x8*)(base + 512) = z;
  *(bf16x8*)(base + 768) = z;
}

// Pack w_ih [1536,4] + biases into the matching W-side K-chunk.
__global__ void __launch_bounds__(256) pack_wih(const float* __restrict__ w_ih,
                                                const float* __restrict__ b_ih,
                                                const float* __restrict__ b_hh,
                                                char* __restrict__ dst) {
  const int row = blockIdx.x * 256 + threadIdx.x;
  if (row >= 1536) return;
  const float* s = w_ih + (size_t)row * 4;
  const float c4 = b_ih[row] + (row < 1024 ? b_hh[row] : 0.f);
  bf16x8 v;
  v[0] = (__bf16)s[0]; v[1] = (__bf16)s[1]; v[2] = (__bf16)s[2]; v[3] = (__bf16)s[3];
  v[4] = (__bf16)c4;   v[5] = (__bf16)0.f; v[6] = (__bf16)0.f; v[7] = (__bf16)0.f;
  char* base = dst + (size_t)(row >> 4) * 1024 + (row & 15) * 16;
  const bf16x8 z = {};
  *(bf16x8*)(base) = v;
  *(bf16x8*)(base + 256) = z;
  *(bf16x8*)(base + 512) = z;
  *(bf16x8*)(base + 768) = z;
}

// Fused GRU cell, 3-buffer depth-2 counted-vmcnt pipeline (T3/T4, isolated on gru).
// Block: 64 rows x 64 chans x 3 gates; K-step 32; 3 x 16KB LDS (3 blocks/CU = 144KB).
// Steady state: vmcnt(4) retires own stage(kg), stage(kg+1) stays in flight across
// the barrier; stage(kg+2) -> buf[(kg+2)%3] (last read compute(kg-1), sealed by
// barrier(kg)). x@w_ih fold rides as stage(16) -> buf1, issued at kg=14.
__global__ void __launch_bounds__(256, 3) gru_fused6(
    const char* __restrict__ Afl, int ca,   // A = hprev FL, K chunks 0..15
    const char* __restrict__ Wfl,           // whh FL [1536,512], nkg=16
    const char* __restrict__ xF,            // [x|1] FL chunks, 1/rowgrp (1KB stride)
    const char* __restrict__ wihF,          // [w_ih|b] FL chunks, 1/W-rowgrp
    const float* __restrict__ b_hh,
    char* __restrict__ Ofl, int co, int kofs)
{
  __shared__ char smem[49152];              // 3 x 16KB
  const int t = threadIdx.x, w = t >> 6, lane = t & 63;
  int bn, bm;
  swz(blockIdx.x, 8, bn, bm);
  const int m0 = bm * 64;
  const int n0 = bn * 64;

  // 16 chunk-slots per K-step: 0..3 = A rowgrps, 4..15 = W (gate g, colgrp cr)
  const char* gsrc[4];
  const char* gsrc16[4];
  int loff[4];
  #pragma unroll
  for (int s = 0; s < 4; ++s) {
    const int idx = w * 4 + s;
    if (idx < 4) {
      gsrc[s]   = Afl + (size_t)((m0 >> 4) + idx) * ca * 1024 + lane * 16;
      gsrc16[s] = xF  + (size_t)((m0 >> 4) + idx) * 1024 + lane * 16;
    } else {
      const int c = idx - 4, g = c >> 2, cr = c & 3;
      gsrc[s]   = Wfl  + (size_t)(g * 32 + (n0 >> 4) + cr) * 16 * 1024 + lane * 16;
      gsrc16[s] = wihF + (size_t)(g * 32 + (n0 >> 4) + cr) * 1024 + lane * 16;
    }
    loff[s] = idx * 1024;
  }

  f32x4 acc[3][4], acc_ni[4];
  const f32x4 zero = {0.f, 0.f, 0.f, 0.f};
  #pragma unroll
  for (int g = 0; g < 3; ++g)
    #pragma unroll
    for (int i = 0; i < 4; ++i) acc[g][i] = zero;
  #pragma unroll
  for (int i = 0; i < 4; ++i) acc_ni[i] = zero;

  // prologue: stage K-steps 0 (buf0) and 1 (buf1)
  #pragma unroll
  for (int s = 0; s < 4; ++s)
    gld_lds16(gsrc[s], smem + loff[s]);
  #pragma unroll
  for (int s = 0; s < 4; ++s)
    gld_lds16(gsrc[s] + 1024, smem + 16384 + loff[s]);

  #pragma unroll
  for (int kg = 0; kg < 16; ++kg) {
    wait_vmcnt<4>();                  // own stage(kg) retired; stage(kg+1) in flight
    __builtin_amdgcn_s_barrier();     // publish all waves' stage(kg)
    __builtin_amdgcn_sched_barrier(0);
    const char* cur = smem + (kg % 3) * 16384;
    if (kg + 2 <= 16) {               // stage(kg+2); kg=14 issues the x/wih chunk
      char* nxt = smem + ((kg + 2) % 3) * 16384;
      #pragma unroll
      for (int s = 0; s < 4; ++s) {
        const char* src = (kg + 2 < 16) ? gsrc[s] + (size_t)(kg + 2) * 1024
                                        : gsrc16[s];
        gld_lds16(src, nxt + loff[s]);
      }
    }
    bf16x8 af[4];
    #pragma unroll
    for (int i = 0; i < 4; ++i)
      af[i] = *(const bf16x8*)(cur + i * 1024 + lane * 16);
    #pragma unroll
    for (int g = 0; g < 3; ++g) {
      const bf16x8 bv = *(const bf16x8*)(cur + (4 + g * 4 + w) * 1024 + lane * 16);
      #pragma unroll
      for (int i = 0; i < 4; ++i)
        acc[g][i] = __builtin_amdgcn_mfma_f32_16x16x32_bf16(af[i], bv, acc[g][i], 0, 0, 0);
    }
  }

  // extra K-step (x-part) from buf[16%3=1]: r,z in place; n-part to acc_ni.
  wait_vmcnt<0>();                    // drain stage(16)
  __builtin_amdgcn_s_barrier();
  __builtin_amdgcn_sched_barrier(0);
  {
    const char* cur = smem + 16384;   // buf1
    bf16x8 af[4];
    #pragma unroll
    for (int i = 0; i < 4; ++i)
      af[i] = *(const bf16x8*)(cur + i * 1024 + lane * 16);
    #pragma unroll
    for (int g = 0; g < 2; ++g) {
      const bf16x8 bv = *(const bf16x8*)(cur + (4 + g * 4 + w) * 1024 + lane * 16);
      #pragma unroll
      for (int i = 0; i < 4; ++i)
        acc[g][i] = __builtin_amdgcn_mfma_f32_16x16x32_bf16(af[i], bv, acc[g][i], 0, 0, 0);
    }
    const bf16x8 bv2 = *(const bf16x8*)(cur + (4 + 8 + w) * 1024 + lane * 16);
    #pragma unroll
    for (int i = 0; i < 4; ++i)
      acc_ni[i] = __builtin_amdgcn_mfma_f32_16x16x32_bf16(af[i], bv2, acc_ni[i], 0, 0, 0);
  }
  // rep lives in buf0; buf0's last reads were compute(15), sealed by the x-step
  // barrier every wave has passed. The x-step reads only buf1 -> no extra sync.

  const int lr = lane & 15, q4 = (lane >> 4) * 4;
  char* rep = smem + w * 2048;  // 4 half-chunks x 512B, wave-private (in buf0)
  const int c = n0 + w * 16 + lr;
  const float bhn = b_hh[c + 1024];
  const int wbase = ((lr >> 3) * 16 + q4) * 16 + (lr & 7) * 2;
  #pragma unroll
  for (int i = 0; i < 4; ++i) {
    #pragma unroll
    for (int r4 = 0; r4 < 4; ++r4) {
      const int row = m0 + i * 16 + q4 + r4;
      const float rr = sigm(acc[0][i][r4]);
      const float zz = sigm(acc[1][i][r4]);
      const float nn = tanh_fast(acc_ni[i][r4] + rr * (acc[2][i][r4] + bhn));
      const float hp = (float)*(const __bf16*)(Afl + fl_off(row, c, ca, 0));
      *(__bf16*)(rep + i * 512 + wbase + r4 * 16) = (__bf16)((1.f - zz) * nn + zz * hp);
    }
  }
  const int rg0 = m0 >> 4;
  const int cg = kofs + (n0 >> 5) + (w >> 1);
  const int half = (w & 1) * 512;
  #pragma unroll
  for (int i = 0; i < 4; ++i) {
    const uint2 v = *(const uint2*)(rep + i * 512 + lane * 8);
    *(uint2*)(Ofl + ((size_t)(rg0 + i) * co + cg) * 1024 + half + lane * 8) = v;
  }
}

// Generic FL GEMM (round-0). Block tile 128 x (NJ*32); wave tile 64 x (NJ*16).
// MODE 2 (fc): O1 = bf16(v) FL ; O2 = bf16(relu(v)) FL — coalesced via LDS repack
template <int NKG, int NJ, int MODE>
__global__ void __launch_bounds__(256, 4) gemm_fl5(
    const char* __restrict__ Afl,
    const char* __restrict__ Bfl, int nbn,
    const float* __restrict__ bias,
    char* __restrict__ O1, char* __restrict__ O2, int co,
    const float* __restrict__ w2, float* __restrict__ dxy)
{
  constexpr int NCH = 8 + 2 * NJ;          // chunks staged per K-step
  constexpr int NS = NCH / 4;              // chunks per wave
  constexpr int BUFB = NCH * 1024;
  __shared__ char smem[2 * BUFB];
  const int t = threadIdx.x, w = t >> 6, lane = t & 63;
  int bn, bm;
  swz(blockIdx.x, nbn, bn, bm);
  const int m0 = bm * 128, n0 = bn * (NJ * 32);
  const int wm = (w >> 1) * 64, wn = (w & 1) * (NJ * 16);

  const char* gsrc[NS];
  int loff[NS];
  #pragma unroll
  for (int s = 0; s < NS; ++s) {
    const int idx = w * NS + s;
    if (idx < 8) gsrc[s] = Afl + (size_t)((m0 >> 4) + idx) * NKG * 1024 + lane * 16;
    else         gsrc[s] = Bfl + (size_t)((n0 >> 4) + idx - 8) * NKG * 1024 + lane * 16;
    loff[s] = idx * 1024;
  }

  f32x4 acc[4][NJ];
  const f32x4 zero = {0.f, 0.f, 0.f, 0.f};
  #pragma unroll
  for (int i = 0; i < 4; ++i)
    #pragma unroll
    for (int j = 0; j < NJ; ++j) acc[i][j] = zero;

  #pragma unroll
  for (int s = 0; s < NS; ++s)
    gld_lds16(gsrc[s], smem + loff[s]);

  #pragma unroll
  for (int kg = 0; kg < NKG; ++kg) {
    __syncthreads();
    const char* cur = smem + (kg & 1) * BUFB;
    if (kg + 1 < NKG) {
      char* nxt = smem + ((kg + 1) & 1) * BUFB;
      #pragma unroll
      for (int s = 0; s < NS; ++s)
        gld_lds16(gsrc[s] + (size_t)(kg + 1) * 1024, nxt + loff[s]);
    }
    bf16x8 af[4], bv[NJ];
    #pragma unroll
    for (int i = 0; i < 4; ++i)
      af[i] = *(const bf16x8*)(cur + ((wm >> 4) + i) * 1024 + lane * 16);
    #pragma unroll
    for (int j = 0; j < NJ; ++j)
      bv[j] = *(const bf16x8*)(cur + (8 + (wn >> 4) + j) * 1024 + lane * 16);
    #pragma unroll
    for (int i = 0; i < 4; ++i)
      #pragma unroll
      for (int j = 0; j < NJ; ++j)
        acc[i][j] = __builtin_amdgcn_mfma_f32_16x16x32_bf16(af[i], bv[j], acc[i][j], 0, 0, 0);
  }

  const int lr = lane & 15, q4 = (lane >> 4) * 4;
  if (MODE == 2) {
    char* rep = smem + w * (NJ / 2) * 1024;
    const int rgb = (m0 >> 4) + (wm >> 4);
    const int cgb = (n0 >> 5) + (wn >> 5);
    for (int i = 0; i < 4; ++i) {
      #pragma unroll
      for (int j = 0; j < NJ; ++j) {
        const int col = n0 + wn + j * 16 + lr;
        const float bvv = bias[col];
        const int wbase = (((j & 1) * 2 + (lr >> 3)) * 16 + q4) * 16 + (lr & 7) * 2;
        #pragma unroll
        for (int r = 0; r < 4; ++r) {
          const float v = acc[i][j][r] + bvv;
          *(__bf16*)(rep + (j >> 1) * 1024 + wbase + r * 16) = (__bf16)v;
        }
      }
      #pragma unroll
      for (int jc = 0; jc < NJ / 2; ++jc) {
        const bf16x8 v = *(const bf16x8*)(rep + jc * 1024 + lane * 16);
        const size_t cb = ((size_t)(rgb + i) * co + cgb + jc) * 1024 + lane * 16;
        *(bf16x8*)(O1 + cb) = v;
        bf16x8 vr;
        #pragma unroll
        for (int e = 0; e < 8; ++e) vr[e] = (__bf16)fmaxf((float)v[e], 0.f);
        *(bf16x8*)(O2 + cb) = vr;
      }
    }
  }
}

// MLP GEMM (+relu+w2 fusion), 8-wave 256x256 tile, BK=32, K=512 (NKG=16).
// 2-buffer (64KB LDS); DPP/VALU-pipe epilogue (round-9 confirmed win).
__global__ void __launch_bounds__(512, 2) mlp2b(
    const char* __restrict__ Afl,   // hxrF FL, nkg=16
    const char* __restrict__ Bfl,   // w1F  FL, nkg=16
    const float* __restrict__ bias, // b1
    const float* __restrict__ w2,   // [4,2048]
    float* __restrict__ dxy)
{
  __shared__ char smem[2 * 32768];
  const int t = threadIdx.x, w = t >> 6, lane = t & 63;
  const int wr = w >> 2, wc = w & 3;
  int bn, bm;
  swz(blockIdx.x, 8, bn, bm);
  const int m0 = bm * 256, n0 = bn * 256;

  const char* gsrc[4];
  int loff[4];
  #pragma unroll
  for (int s = 0; s < 4; ++s) {
    const int idx = w * 4 + s;
    if (idx < 16) {
      gsrc[s] = Afl + (size_t)((m0 >> 4) + idx) * 16 * 1024 + lane * 16;
      loff[s] = idx * 1024;
    } else {
      gsrc[s] = Bfl + (size_t)((n0 >> 4) + idx - 16) * 16 * 1024 + lane * 16;
      loff[s] = 16384 + (idx - 16) * 1024;
    }
  }

  f32x4 acc[8][4];
  const f32x4 zero = {0.f, 0.f, 0.f, 0.f};
  #pragma unroll
  for (int i = 0; i < 8; ++i)
    #pragma unroll
    for (int j = 0; j < 4; ++j) acc[i][j] = zero;

  #pragma unroll
  for (int s = 0; s < 4; ++s)
    gld_lds16(gsrc[s], smem + loff[s]);

  #pragma unroll
  for (int kg = 0; kg < 16; ++kg) {
    __syncthreads();
    const char* cur = smem + (kg & 1) * 32768;
    if (kg + 1 < 16) {
      char* nxt = smem + ((kg + 1) & 1) * 32768;
      #pragma unroll
      for (int s = 0; s < 4; ++s)
        gld_lds16(gsrc[s] + (size_t)(kg + 1) * 1024, nxt + loff[s]);
    }
    bf16x8 af[8], bv[4];
    #pragma unroll
    for (int j = 0; j < 4; ++j)
      bv[j] = *(const bf16x8*)(cur + 16384 + (wc * 4 + j) * 1024 + lane * 16);
    #pragma unroll
    for (int i = 0; i < 8; ++i)
      af[i] = *(const bf16x8*)(cur + (wr * 8 + i) * 1024 + lane * 16);
    __builtin_amdgcn_s_setprio(1);
    #pragma unroll
    for (int i = 0; i < 8; ++i)
      #pragma unroll
      for (int j = 0; j < 4; ++j)
        acc[i][j] = __builtin_amdgcn_mfma_f32_16x16x32_bf16(af[i], bv[j], acc[i][j], 0, 0, 0);
    __builtin_amdgcn_s_setprio(0);
  }

  const int lr = lane & 15, q4 = (lane >> 4) * 4;
  const int slice = bn * 4 + wc;
  float bvv[4], w2c[4][4];
  #pragma unroll
  for (int j = 0; j < 4; ++j) {
    const int col = n0 + wc * 64 + j * 16 + lr;
    bvv[j] = bias[col];
    w2c[j][0] = w2[col];        w2c[j][1] = w2[2048 + col];
    w2c[j][2] = w2[4096 + col]; w2c[j][3] = w2[6144 + col];
  }
  #pragma unroll
  for (int i = 0; i < 8; ++i) {
    float v[4][4];
    #pragma unroll
    for (int r = 0; r < 4; ++r)
      #pragma unroll
      for (int o = 0; o < 4; ++o) v[r][o] = 0.f;
    #pragma unroll
    for (int j = 0; j < 4; ++j) {
      #pragma unroll
      for (int r = 0; r < 4; ++r) {
        const float pv = fmaxf(acc[i][j][r] + bvv[j], 0.f);
        v[r][0] += pv * w2c[j][0]; v[r][1] += pv * w2c[j][1];
        v[r][2] += pv * w2c[j][2]; v[r][3] += pv * w2c[j][3];
      }
    }
    #pragma unroll
    for (int r = 0; r < 4; ++r)
      #pragma unroll
      for (int o = 0; o < 4; ++o) v[r][o] = red16(v[r][o]);
    if (lr == 0) {
      #pragma unroll
      for (int r = 0; r < 4; ++r) {
        const int row = m0 + wr * 128 + i * 16 + q4 + r;
        float4 vv = make_float4(v[r][0], v[r][1], v[r][2], v[r][3]);
        *(float4*)(dxy + ((size_t)slice * Bsz + row) * 4) = vv;
      }
    }
  }
}

// xy += sum(dxy slices) + b2; out[:,istep,:] = xy; also refresh xyF ([xy|1] FL chunk).
__global__ void __launch_bounds__(256) finalize(
    const float* __restrict__ dxy, const float* __restrict__ b2,
    float* __restrict__ xy, float* __restrict__ out, int istep,
    char* __restrict__ xyF)
{
  const int b = blockIdx.x * 256 + threadIdx.x;
  float4 s = *(const float4*)b2;
  #pragma unroll 8
  for (int sl = 0; sl < 32; ++sl) {
    const float4 d = *(const float4*)(dxy + ((size_t)sl * Bsz + b) * 4);
    s.x += d.x; s.y += d.y; s.z += d.z; s.w += d.w;
  }
  float4 xv = *(const float4*)(xy + (size_t)b * 4);
  xv.x += s.x; xv.y += s.y; xv.z += s.z; xv.w += s.w;
  *(float4*)(xy + (size_t)b * 4) = xv;
  *(float4*)(out + (size_t)b * 20 + istep * 4) = xv;
  bf16x8 v;
  v[0] = (__bf16)xv.x; v[1] = (__bf16)xv.y; v[2] = (__bf16)xv.z; v[3] = (__bf16)xv.w;
  v[4] = (__bf16)1.0f; v[5] = (__bf16)0.f; v[6] = (__bf16)0.f; v[7] = (__bf16)0.f;
  *(bf16x8*)(xyF + (size_t)(b >> 4) * 1024 + (b & 15) * 16) = v;
}

extern "C" void kernel_launch(void* const* d_in, const int* in_sizes, int n_in,
                              void* d_out, int out_size, void* d_ws, size_t ws_size,
                              hipStream_t stream)
{
  const float* pv   = (const float*)d_in[0];
  const float* ptf  = (const float*)d_in[1];
  const float* w_ih = (const float*)d_in[2];
  const float* w_hh = (const float*)d_in[3];
  const float* b_ih = (const float*)d_in[4];
  const float* b_hh = (const float*)d_in[5];
  const float* w_fc = (const float*)d_in[6];
  const float* b_fc = (const float*)d_in[7];
  const float* w1   = (const float*)d_in[8];
  const float* b1   = (const float*)d_in[9];
  const float* w2   = (const float*)d_in[10];
  const float* b2   = (const float*)d_in[11];
  float* out = (float*)d_out;

  char* p = (char*)d_ws;
  auto carve = [&](size_t bytes) {
    char* r = p;
    p += (bytes + 255) & ~(size_t)255;
    return r;
  };
  char*  hxF   = carve((size_t)Bsz * 512 * 2);     // FL ca=16
  char*  hxrF  = carve((size_t)Bsz * 512 * 2);     // FL ca=16
  char*  hcatF = carve((size_t)Bsz * 1024 * 2);    // FL ca=32: h1 kg 0..15, h2 kg 16..31
  float* dxy   = (float*)carve((size_t)32 * Bsz * 4 * 4);
  float* xy    = (float*)carve((size_t)Bsz * 4 * 4);
  char*  whhF  = carve((size_t)1536 * 512 * 2);    // FL nkg=16
  char*  wfcF  = carve((size_t)512 * 1024 * 2);    // FL nkg=32
  char*  w1F   = carve((size_t)2048 * 512 * 2);    // FL nkg=16
  char*  xyF   = carve((size_t)1024 * 1024);       // [xy|1] FL chunks
  char*  pvF   = carve((size_t)5 * 1024 * 1024);   // [pv_i|1] FL chunks, 1MB/slice
  char*  wihF  = carve((size_t)96 * 1024);         // [w_ih|b] FL chunks

  pack_fl<<<(1536 * 512 / 8 + 255) / 256, 256, 0, stream>>>(w_hh, whhF, 512, 4, 1536 * 512 / 8);
  pack_fl<<<(512 * 1024 / 8 + 255) / 256, 256, 0, stream>>>(w_fc, wfcF, 1024, 5, 512 * 1024 / 8);
  pack_fl<<<(2048 * 512 / 8 + 255) / 256, 256, 0, stream>>>(w1, w1F, 512, 4, 2048 * 512 / 8);
  pack_fl<<<(Bsz * 512 / 8 + 255) / 256, 256, 0, stream>>>(ptf, hxF, 512, 4, Bsz * 512 / 8);
  pack_wih<<<6, 256, 0, stream>>>(w_ih, b_ih, b_hh, wihF);
  pack_x<<<(Bsz * HORsz + 255) / 256, 256, 0, stream>>>(pv, HORsz * 4, pvF, Bsz * HORsz);
  hipMemsetAsync(xy, 0, (size_t)Bsz * 4 * 4, stream);
  pack_x<<<Bsz / 256, 256, 0, stream>>>(xy, 4, xyF, Bsz);   // xy=0 -> cols 0-3=0, col4=1

  for (int i = 0; i < HORsz; ++i) {
    // h1 = GRUCell(xy, hx) -> hcat kg 0..15
    gru_fused6<<<2048, 256, 0, stream>>>(
        hxF, 16, whhF, xyF, wihF, b_hh, hcatF, 32, 0);
    // h2 = GRUCell(pv[:,i], h1) -> hcat kg 16..31
    gru_fused6<<<2048, 256, 0, stream>>>(
        hcatF, 32, whhF, pvF + (size_t)i * 1048576, wihF, b_hh, hcatF, 32, 16);
    // hx = hcat @ w_fc^T + b_fc ; hxr = relu(hx)
    gemm_fl5<32, 2, 2><<<1024, 256, 0, stream>>>(
        hcatF, wfcF, 8, b_fc, hxF, hxrF, 16, nullptr, nullptr);
    // dxy partials = relu(relu-gemm) @ w2^T  (256^2 8-wave, DPP epilogue)
    mlp2b<<<512, 512, 0, stream>>>(hxrF, w1F, b1, w2, dxy);
    // xy += sum + b2; out; refresh xyF
    finalize<<<Bsz / 256, 256, 0, stream>>>(dxy, b2, xy, out, i, xyF);
  }
}